// Round 6
// baseline (872.672 us; speedup 1.0000x reference)
//
#include <hip/hip_runtime.h>
#include <hip/hip_bf16.h>
#include <math.h>

// Problem constants
#define BB 4
#define MM 20
#define LL 200
#define INC 2048
#define C1 512
#define C2 256
#define CDIM 300
#define DC1 512
#define DC2 256
#define SDIM 1024
#define BM 80           // B*M
#define L2 100          // L/2
#define L4 50           // L/4

typedef unsigned short u16;
typedef __attribute__((ext_vector_type(8))) short bf16x8;
typedef __attribute__((ext_vector_type(4))) float f32x4;

__device__ __forceinline__ u16 f2bf_rne(float f) {
  unsigned u = __float_as_uint(f);
  unsigned r = u + 0x7FFFu + ((u >> 16) & 1u);
  return (u16)(r >> 16);
}
__device__ __forceinline__ float bf2f(u16 v) {
  return __uint_as_float(((unsigned)v) << 16);
}

// async global -> LDS, 16 B per lane. LDS dest = wave-uniform base + lane*16.
__device__ __forceinline__ void gload16(const u16* g, u16* l) {
  __builtin_amdgcn_global_load_lds(
      (const __attribute__((address_space(1))) void*)g,
      (__attribute__((address_space(3))) void*)l, 16, 0, 0);
}

// ================= MEGA-PREP: all independent prep work in ONE dispatch =================
// Region map (blockIdx.x):
//   [0, 16320)          cast+pad+swizzle batch -> batchb [80][204][2048]
//   [16320, 16832)      conv1 weight [co][ci][5] -> [co][5][ci]   (512 co-blocks)
//   [16832, 17088)      conv2 weight transpose                     (256)
//   [17088, 17472)      deconv1 weight -> per-parity               (384)
//   [17472, 17600)      deconv2 weight -> per-parity               (128)
//   [17600, 17632)      w_ca2 fp32->bf16                           (32)
//   [17632, 17640)      small q/v precompute                       (8)
//   [17640, 17720)      t1b pad-row zeroing                        (80)
// All regions write disjoint buffers and read only kernel inputs -> no deps.
__global__ __launch_bounds__(256) void k_prep_all(
    const float* __restrict__ batch, const float* __restrict__ w_conv1,
    const float* __restrict__ w_conv2, const float* __restrict__ w_dc1,
    const float* __restrict__ w_dc2, const float* __restrict__ w_ca2,
    const float* __restrict__ concept1, const float* __restrict__ concept2,
    const float* __restrict__ w_ca1, const float* __restrict__ w_sim1,
    const float* __restrict__ w_sim2, const float* __restrict__ w_mlp,
    u16* __restrict__ batchb, u16* __restrict__ w1b, u16* __restrict__ w2b,
    u16* __restrict__ wd1p, u16* __restrict__ wd2p, u16* __restrict__ wca2b,
    float* __restrict__ qv, u16* __restrict__ t1b) {
  __shared__ __align__(16) u16 sh[10240];   // 20 KB, reused per-branch
  int bid = blockIdx.x;
  int tid = threadIdx.x;

  if (bid < 16320) {
    // ---- batch fp32 -> bf16, 2-row zero pad, global XOR-swizzle ----
    int idx = bid * 256 + tid;
    int c8 = idx % 256;
    int pi = (idx / 256) % 204;
    int n  = idx / (256 * 204);
    uint4 o = make_uint4(0u, 0u, 0u, 0u);
    if (pi >= 2 && pi < 202) {
      const float* p = batch + ((long long)(n * 200 + pi - 2) * 2048 + c8 * 8);
      float4 a = *(const float4*)p;
      float4 b = *(const float4*)(p + 4);
      o.x = (unsigned)f2bf_rne(a.x) | ((unsigned)f2bf_rne(a.y) << 16);
      o.y = (unsigned)f2bf_rne(a.z) | ((unsigned)f2bf_rne(a.w) << 16);
      o.z = (unsigned)f2bf_rne(b.x) | ((unsigned)f2bf_rne(b.y) << 16);
      o.w = (unsigned)f2bf_rne(b.z) | ((unsigned)f2bf_rne(b.w) << 16);
    }
    int key = (n * 204 + pi) & 7;
    long long pos = ((long long)(n * 204 + pi)) * 256 + (c8 ^ key);
    *(uint4*)(batchb + pos * 8) = o;
  } else if (bid < 17088) {
    // ---- conv weight [co][ci][t] -> [co][t][ci] via per-co LDS transpose ----
    const float* in; u16* out; int Cin, co;
    if (bid < 16832) { in = w_conv1; out = w1b; Cin = INC; co = bid - 16320; }
    else             { in = w_conv2; out = w2b; Cin = C1;  co = bid - 16832; }
    int n = Cin * 5;
    const float* src = in + (long long)co * n;
    for (int i = tid; i < n; i += 256) sh[i] = f2bf_rne(src[i]);
    __syncthreads();
    u16* dst = out + (long long)co * n;
    int n8 = n >> 3;
    for (int j8 = tid; j8 < n8; j8 += 256) {
      int j = j8 * 8;
      int t = j / Cin, ci = j - t * Cin;
      u16 tmp[8];
      #pragma unroll
      for (int e = 0; e < 8; ++e) tmp[e] = sh[(ci + e) * 5 + t];
      uint4 o;
      o.x = tmp[0] | ((unsigned)tmp[1] << 16);
      o.y = tmp[2] | ((unsigned)tmp[3] << 16);
      o.z = tmp[4] | ((unsigned)tmp[5] << 16);
      o.w = tmp[6] | ((unsigned)tmp[7] << 16);
      *(uint4*)&dst[j] = o;
    }
  } else if (bid < 17600) {
    // ---- deconv weight [ci][co][4] -> [z][co][tt][ci], t = 3-z-2tt ----
    u16 (*l)[65] = (u16(*)[65])sh;
    const float* in; u16* out; int Cin, Cout, b2;
    if (bid < 17472) { in = w_dc1; out = wd1p; Cin = 3 * C2; Cout = DC1; b2 = bid - 17088; }
    else             { in = w_dc2; out = wd2p; Cin = DC1;    Cout = DC2; b2 = bid - 17472; }
    int C = Cout * 4;
    int nci = Cin >> 6;
    int ci0 = (b2 % nci) << 6;
    int c0  = (b2 / nci) << 6;
    int cc = tid & 63, rr = tid >> 6;
    #pragma unroll 4
    for (int p = 0; p < 16; ++p) {
      int r = rr + p * 4;
      l[r][cc] = f2bf_rne(in[(long long)(ci0 + r) * C + c0 + cc]);
    }
    __syncthreads();
    #pragma unroll 4
    for (int p = 0; p < 16; ++p) {
      int cl = rr + p * 4;
      int c = c0 + cl;
      int co = c >> 2, t = c & 3;
      int z = (3 - t) & 1, tt = (3 - t) >> 1;
      out[(((long long)z * Cout + co) * 2 + tt) * Cin + ci0 + cc] = l[cc][cl];
    }
  } else if (bid < 17632) {
    // ---- w_ca2 fp32 -> bf16 ----
    int idx = (bid - 17600) * 256 + tid;
    const float4* p = (const float4*)w_ca2 + (long long)idx * 2;
    float4 a = p[0], b = p[1];
    uint4 o;
    o.x = (unsigned)f2bf_rne(a.x) | ((unsigned)f2bf_rne(a.y) << 16);
    o.y = (unsigned)f2bf_rne(a.z) | ((unsigned)f2bf_rne(a.w) << 16);
    o.z = (unsigned)f2bf_rne(b.x) | ((unsigned)f2bf_rne(b.y) << 16);
    o.w = (unsigned)f2bf_rne(b.z) | ((unsigned)f2bf_rne(b.w) << 16);
    *(uint4*)(wca2b + (long long)idx * 8) = o;
  } else if (bid < 17640) {
    // ---- small q/v precompute ----
    float* cvec = (float*)sh;            // [300]
    float* chat = (float*)sh + 320;      // [1024]  (total 5.3 KB < 20 KB)
    int b2 = bid - 17632;
    int cz = b2 >> 2;
    int b  = b2 & 3;
    const float* con = cz ? concept2 : concept1;
    for (int j = tid; j < CDIM; j += 256) cvec[j] = con[b * CDIM + j];
    __syncthreads();
    float accq = 0.f;
    for (int j = 0; j < CDIM; ++j) accq += cvec[j] * w_ca1[tid * CDIM + j];
    qv[(cz * 4 + b) * 256 + tid] = accq;
    for (int i = 0; i < 4; ++i) {
      int s = tid + i * 256;
      float a2 = 0.f;
      for (int j = 0; j < CDIM; ++j) a2 += cvec[j] * w_sim2[s * CDIM + j];
      chat[s] = a2 * w_mlp[s];
    }
    __syncthreads();
    float v = 0.f;
    for (int s = 0; s < SDIM; ++s) v += w_sim1[s * 256 + tid] * chat[s];
    qv[2048 + (cz * 4 + b) * 256 + tid] = v;
  } else {
    // ---- t1b pad-row zeroing: [80][104][512], rows {0,1,102,103} ----
    int idx = (bid - 17640) * 256 + tid;   // < 20480
    int c = idx % 64;
    int pr = (idx / 64) % 4;
    int n = idx / 256;
    int row = (pr < 2) ? pr : 100 + pr;
    *(uint4*)(t1b + ((long long)(n * 104 + row) * 64 + c) * 8) = make_uint4(0, 0, 0, 0);
  }
}

// ---------------- post-conv1 zero-pads (catm rows {0,51}, d1b rows {0,101}) ----------------
__global__ void k_zero_pad2(u16* __restrict__ catm, u16* __restrict__ d1b) {
  int idx = blockIdx.x * 256 + threadIdx.x;
  if (idx < 15360) {
    int c = idx % 96;
    int pr = (idx / 96) & 1;
    int n = idx / 192;
    int row = pr ? 51 : 0;
    *(uint4*)(catm + ((long long)(n * 52 + row) * 96 + c) * 8) = make_uint4(0, 0, 0, 0);
  } else {
    int j = idx - 15360;      // < 10240
    int c = j % 64;
    int pr = (j / 64) & 1;
    int n = j / 128;
    int row = pr ? 101 : 0;
    *(uint4*)(d1b + ((long long)(n * 102 + row) * 64 + c) * 8) = make_uint4(0, 0, 0, 0);
  }
}

// ======================= conv GEMM with A-dedup (128-row tile) =======================
// R3-verified structure (see earlier rounds). Shared device body; named wrappers
// per call site so rocprof shows each dispatch separately.
template <int SWZO>
__device__ __forceinline__ void gemm_conv_body(
    const u16* __restrict__ A, const u16* __restrict__ Bw,
    u16* __restrict__ Co, const float* __restrict__ bias,
    int M, int N, int Ktot, int cin, int ncib,
    int lr, int rpad, int px, int yspan, int gy,
    int orpad, int ooff, long long aend) {
  __shared__ __align__(16) u16 At[2][10240];   // [2][160][64]
  __shared__ __align__(16) u16 Bs[2][8192];
  int id = blockIdx.x;
  int k8 = id & 7, j = id >> 3;
  int x = k8 / px, h = k8 - x * px;
  int y = h * yspan + j;
  if (y >= gy) return;
  int row0 = y * 128, col0 = x * 128;
  int tid = threadIdx.x, w = tid >> 6, ln = tid & 63;
  int r15 = ln & 15, q = ln >> 4;

  int n0 = row0 / lr, l0 = row0 - n0 * lr;
  long long prow0 = (long long)n0 * rpad + l0;

  int wrb = (w >> 1) * 64;
  int rlb[4], pp[4];
  #pragma unroll
  for (int mi = 0; mi < 4; ++mi) {
    int rr = wrb + mi * 16 + r15;
    int nc = (row0 + rr) / lr - n0;
    rlb[mi] = rr + 4 * nc;
    pp[mi] = (int)((prow0 + rlb[mi]) & 7);
  }

  long long arow_base = prow0 + w * 40 + (ln >> 3);
  const u16* alim = A + (aend - 8);
  auto stA = [&](int cib_, int pc) {
    const u16* src = A + (arow_base + pc * 8) * cin + cib_ * 64 + (ln & 7) * 8;
    if (src > alim) src = alim;
    gload16(src, At[cib_ & 1] + (w * 40 + pc * 8) * 64);
  };

  const u16* gb[4];
  #pragma unroll
  for (int i = 0; i < 4; ++i) {
    int f = 4 * w + i, blk = f >> 1, ks = f & 1;
    int klocal = ks * 32 + q * 8;
    int br = col0 + blk * 16 + r15;
    gb[i] = Bw + ((long long)br * Ktot + klocal);
  }
  int wbase = 4 * w * 512;

  f32x4 acc[4][4];
  #pragma unroll
  for (int i = 0; i < 4; ++i)
    #pragma unroll
    for (int j2 = 0; j2 < 4; ++j2) acc[i][j2] = (f32x4){0.f, 0.f, 0.f, 0.f};
  int wc2 = (w & 1) * 4;

  #pragma unroll
  for (int pc = 0; pc < 5; ++pc) stA(0, pc);
  #pragma unroll
  for (int i = 0; i < 4; ++i) gload16(gb[i], Bs[0] + wbase + i * 512);
  #pragma unroll
  for (int i = 0; i < 4; ++i) gb[i] += cin;
  int ts = 1;
  asm volatile("s_waitcnt vmcnt(0)" ::: "memory");
  __builtin_amdgcn_s_barrier();

  long long bwrap = 64 - 4 * (long long)cin;
  for (int cib = 0; cib < ncib; ++cib) {
    bool lastcib = (cib == ncib - 1);
    #pragma unroll
    for (int t = 0; t < 5; ++t) {
      bool lastc = lastcib && (t == 4);
      if (!lastcib) stA(cib + 1, t);
      if (!lastc) {
        int bufn = (cib + t + 1) & 1;
        #pragma unroll
        for (int i = 0; i < 4; ++i) gload16(gb[i], Bs[bufn] + wbase + i * 512);
        long long d = (ts == 4) ? bwrap : (long long)cin;
        ts = (ts == 4) ? 0 : ts + 1;
        #pragma unroll
        for (int i = 0; i < 4; ++i) gb[i] += d;
      }
      if (lastc)        asm volatile("s_waitcnt vmcnt(0)" ::: "memory");
      else if (lastcib) asm volatile("s_waitcnt vmcnt(4)" ::: "memory");
      else              asm volatile("s_waitcnt vmcnt(5)" ::: "memory");
      __builtin_amdgcn_s_barrier();
      __builtin_amdgcn_sched_barrier(0);
      const u16* Ab = At[cib & 1];
      const u16* Bb = Bs[(cib + t) & 1];
      int rof[4], pr8[4];
      #pragma unroll
      for (int mi = 0; mi < 4; ++mi) {
        rof[mi] = (rlb[mi] + t) * 64;
        pr8[mi] = (pp[mi] + t) & 7;
      }
      #pragma unroll
      for (int ks = 0; ks < 2; ++ks) {
        bf16x8 af[4], bf[4];
        #pragma unroll
        for (int mi = 0; mi < 4; ++mi)
          af[mi] = *(const bf16x8*)&Ab[rof[mi] + (((ks * 4 + q) ^ pr8[mi]) * 8)];
        #pragma unroll
        for (int ni = 0; ni < 4; ++ni)
          bf[ni] = *(const bf16x8*)&Bb[(((wc2 + ni) * 2 + ks) * 512) + ln * 8];
        #pragma unroll
        for (int mi = 0; mi < 4; ++mi)
          #pragma unroll
          for (int ni = 0; ni < 4; ++ni)
            acc[mi][ni] = __builtin_amdgcn_mfma_f32_16x16x32_bf16(
                af[mi], bf[ni], acc[mi][ni], 0, 0, 0);
      }
      __builtin_amdgcn_sched_barrier(0);
      __builtin_amdgcn_s_barrier();
    }
  }

  int q4 = q * 4;
  int wrow = (w >> 1) * 64, wcol = (w & 1) * 64;
  int lrh = lr >> 1;
  #pragma unroll
  for (int mi = 0; mi < 4; ++mi) {
    int gbase = row0 + wrow + mi * 16 + q4;
    #pragma unroll
    for (int p = 0; p < 2; ++p) {
      int grow = gbase + 2 * p;
      if (grow < M) {
        int prow = grow >> 1;
        int n = prow / lrh, ll = prow - n * lrh;
        long long orow = (long long)n * orpad + ooff + ll;
        int key = SWZO ? ((int)(orow & 7) << 3) : 0;
        #pragma unroll
        for (int ni = 0; ni < 4; ++ni) {
          int col = col0 + wcol + ni * 16 + r15;
          float v = fmaxf(acc[mi][ni][2 * p], acc[mi][ni][2 * p + 1]) + bias[col];
          Co[orow * N + (col ^ key)] = f2bf_rne(v);
        }
      }
    }
  }
}

__global__ __launch_bounds__(256) void k_conv1_gemm(
    const u16* __restrict__ A, const u16* __restrict__ Bw,
    u16* __restrict__ Co, const float* __restrict__ bias,
    int M, int N, int Ktot, int cin, int ncib, int lr, int rpad,
    int px, int yspan, int gy, int orpad, int ooff, long long aend) {
  gemm_conv_body<1>(A, Bw, Co, bias, M, N, Ktot, cin, ncib, lr, rpad,
                    px, yspan, gy, orpad, ooff, aend);
}
__global__ __launch_bounds__(256) void k_conv2_gemm(
    const u16* __restrict__ A, const u16* __restrict__ Bw,
    u16* __restrict__ Co, const float* __restrict__ bias,
    int M, int N, int Ktot, int cin, int ncib, int lr, int rpad,
    int px, int yspan, int gy, int orpad, int ooff, long long aend) {
  gemm_conv_body<0>(A, Bw, Co, bias, M, N, Ktot, cin, ncib, lr, rpad,
                    px, yspan, gy, orpad, ooff, aend);
}

// ---------------- generic bf16-MFMA NT GEMM body (kproj, deconvs) ----------------
#define EP_PLAIN 0
#define EP_POOL  1
#define EP_ILV   2

template <int EP>
__device__ __forceinline__ void gemm_body(
    const u16* __restrict__ A, const u16* __restrict__ Bw,
    void* __restrict__ Co, const float* __restrict__ bias,
    int M, int N, int Ktot, int nchunk,
    int lr, int rpad, int cin, int off0c, int taps,
    int px, int yspan, int gy, long long sB, int orpad, int ooff) {
  __shared__ __align__(16) u16 As[2][8192];
  __shared__ __align__(16) u16 Bs[2][8192];
  int id = blockIdx.x;
  int k8 = id & 7, j = id >> 3;
  int x = k8 / px, h = k8 - x * px;
  int y = h * yspan + j;
  if (y >= gy) return;
  int z = blockIdx.z;
  int off0 = (EP == EP_ILV) ? z : off0c;
  int row0 = y * 128, col0 = x * 128;
  int tid = threadIdx.x, w = tid >> 6, ln = tid & 63;
  const u16* Bz = Bw + (long long)z * sB;

  const u16* ga[4];
  const u16* gb[4];
  #pragma unroll
  for (int i = 0; i < 4; ++i) {
    int f = 4 * w + i, blk = f >> 1, ks = f & 1;
    int klocal = ks * 32 + (ln >> 4) * 8;
    int ar = row0 + blk * 16 + (ln & 15);
    int n_ = ar / lr, l_ = ar - n_ * lr;
    ga[i] = A + ((long long)(n_ * rpad + l_ + off0) * cin + klocal);
    int br = col0 + blk * 16 + (ln & 15);
    gb[i] = Bz + ((long long)br * Ktot + klocal);
  }
  int wbase = 4 * w * 512;

  f32x4 acc[4][4];
  #pragma unroll
  for (int i = 0; i < 4; ++i)
    #pragma unroll
    for (int j2 = 0; j2 < 4; ++j2) acc[i][j2] = (f32x4){0.f, 0.f, 0.f, 0.f};

  int wr2 = (w >> 1) * 4;
  int wc2 = (w & 1) * 4;

  long long dstep = cin;
  long long dwrap = 64 - (long long)(taps - 1) * cin;
  int tc = 0;

  #pragma unroll
  for (int i = 0; i < 4; ++i) {
    gload16(ga[i], As[0] + wbase + i * 512);
    gload16(gb[i], Bs[0] + wbase + i * 512);
  }
  {
    long long d = (tc == taps - 1) ? dwrap : dstep;
    tc = (tc == taps - 1) ? 0 : tc + 1;
    #pragma unroll
    for (int i = 0; i < 4; ++i) { ga[i] += d; gb[i] += d; }
  }

  for (int c = 0; c < nchunk; ++c) {
    int cur = c & 1;
    if (c + 1 < nchunk) {
      u16* dA = As[cur ^ 1] + wbase;
      u16* dB = Bs[cur ^ 1] + wbase;
      #pragma unroll
      for (int i = 0; i < 4; ++i) {
        gload16(ga[i], dA + i * 512);
        gload16(gb[i], dB + i * 512);
      }
      long long d = (tc == taps - 1) ? dwrap : dstep;
      tc = (tc == taps - 1) ? 0 : tc + 1;
      #pragma unroll
      for (int i = 0; i < 4; ++i) { ga[i] += d; gb[i] += d; }
      asm volatile("s_waitcnt vmcnt(8)" ::: "memory");
    } else {
      asm volatile("s_waitcnt vmcnt(0)" ::: "memory");
    }
    __builtin_amdgcn_s_barrier();
    __builtin_amdgcn_sched_barrier(0);
    #pragma unroll
    for (int ks = 0; ks < 2; ++ks) {
      bf16x8 af[4], bf[4];
      #pragma unroll
      for (int mi = 0; mi < 4; ++mi)
        af[mi] = *(const bf16x8*)&As[cur][(((wr2 + mi) * 2 + ks) * 512) + ln * 8];
      #pragma unroll
      for (int ni = 0; ni < 4; ++ni)
        bf[ni] = *(const bf16x8*)&Bs[cur][(((wc2 + ni) * 2 + ks) * 512) + ln * 8];
      #pragma unroll
      for (int mi = 0; mi < 4; ++mi)
        #pragma unroll
        for (int ni = 0; ni < 4; ++ni)
          acc[mi][ni] = __builtin_amdgcn_mfma_f32_16x16x32_bf16(
              af[mi], bf[ni], acc[mi][ni], 0, 0, 0);
    }
    __builtin_amdgcn_sched_barrier(0);
    __builtin_amdgcn_s_barrier();
  }

  int c15 = ln & 15, q4 = (ln >> 4) * 4;
  int wrow = (w >> 1) * 64, wcol = (w & 1) * 64;
  if (EP == EP_PLAIN) {
    float* Cz = (float*)Co;
    #pragma unroll
    for (int mi = 0; mi < 4; ++mi) {
      int gbase = row0 + wrow + mi * 16 + q4;
      #pragma unroll
      for (int r = 0; r < 4; ++r) {
        int grow = gbase + r;
        if (grow < M) {
          #pragma unroll
          for (int ni = 0; ni < 4; ++ni) {
            int col = col0 + wcol + ni * 16 + c15;
            Cz[(long long)grow * N + col] = acc[mi][ni][r];
          }
        }
      }
    }
  } else {  // EP_ILV
    u16* Cz = (u16*)Co;
    #pragma unroll
    for (int mi = 0; mi < 4; ++mi) {
      int gbase = row0 + wrow + mi * 16 + q4;
      #pragma unroll
      for (int r = 0; r < 4; ++r) {
        int grow = gbase + r;
        if (grow < M) {
          int n = grow / lr, l = grow - n * lr;
          long long orow = (long long)n * orpad + ooff + 2 * l + z;
          #pragma unroll
          for (int ni = 0; ni < 4; ++ni) {
            int col = col0 + wcol + ni * 16 + c15;
            Cz[orow * N + col] = f2bf_rne(acc[mi][ni][r] + bias[col]);
          }
        }
      }
    }
  }
}

__global__ __launch_bounds__(256) void k_kproj_gemm(
    const u16* __restrict__ A, const u16* __restrict__ Bw,
    void* __restrict__ Co, const float* __restrict__ bias,
    int M, int N, int Ktot, int nchunk, int lr, int rpad, int cin, int off0c,
    int taps, int px, int yspan, int gy, long long sB, int orpad, int ooff) {
  gemm_body<EP_PLAIN>(A, Bw, Co, bias, M, N, Ktot, nchunk, lr, rpad, cin, off0c,
                      taps, px, yspan, gy, sB, orpad, ooff);
}
__global__ __launch_bounds__(256) void k_dc1_gemm(
    const u16* __restrict__ A, const u16* __restrict__ Bw,
    void* __restrict__ Co, const float* __restrict__ bias,
    int M, int N, int Ktot, int nchunk, int lr, int rpad, int cin, int off0c,
    int taps, int px, int yspan, int gy, long long sB, int orpad, int ooff) {
  gemm_body<EP_ILV>(A, Bw, Co, bias, M, N, Ktot, nchunk, lr, rpad, cin, off0c,
                    taps, px, yspan, gy, sB, orpad, ooff);
}
__global__ __launch_bounds__(256) void k_dc2_gemm(
    const u16* __restrict__ A, const u16* __restrict__ Bw,
    void* __restrict__ Co, const float* __restrict__ bias,
    int M, int N, int Ktot, int nchunk, int lr, int rpad, int cin, int off0c,
    int taps, int px, int yspan, int gy, long long sB, int orpad, int ooff) {
  gemm_body<EP_ILV>(A, Bw, Co, bias, M, N, Ktot, nchunk, lr, rpad, cin, off0c,
                    taps, px, yspan, gy, sB, orpad, ooff);
}

// ---------------- attention: wave-parallel scores + softmax + weighted sum ----------------
__global__ __launch_bounds__(256) void k_attention(
    const float* __restrict__ kproj, const u16* __restrict__ t2b,
    const float* __restrict__ qv, const float* __restrict__ w_ca3,
    const int* __restrict__ seg_len, u16* __restrict__ rb) {
  int bm = blockIdx.x % BM;
  int cz = blockIdx.x / BM;
  int b = bm / MM;
  int tid = threadIdx.x, w = tid >> 6, ln = tid & 63;
  __shared__ float sq[256], sw[256], sa[L4 + 14];
  sq[tid] = qv[(cz * 4 + b) * 256 + tid];
  sw[tid] = w_ca3[tid];
  __syncthreads();
  int kmax = (seg_len[bm] + 3) >> 2;
  for (int k = w; k < L4; k += 4) {
    float val = 0.f;
    #pragma unroll
    for (int i = 0; i < 4; ++i) {
      int c = ln + 64 * i;
      val += tanhf(sq[c] + kproj[(bm * L4 + k) * 256 + c]) * sw[c];
    }
    for (int off = 32; off > 0; off >>= 1) val += __shfl_down(val, off, 64);
    if (ln == 0) sa[k] = (k < kmax) ? val : -1e15f;
  }
  __syncthreads();
  if (w == 0) {
    float sv = (ln < L4) ? sa[ln] : -3e38f;
    float mx = sv;
    for (int off = 32; off > 0; off >>= 1) mx = fmaxf(mx, __shfl_down(mx, off, 64));
    mx = __shfl(mx, 0, 64);
    float e = (ln < L4) ? expf(sv - mx) : 0.f;
    float s = e;
    for (int off = 32; off > 0; off >>= 1) s += __shfl_down(s, off, 64);
    s = __shfl(s, 0, 64);
    if (ln < L4) sa[ln] = e / s;
  }
  __syncthreads();
  float r = 0.f;
  for (int k = 0; k < L4; ++k) r += sa[k] * bf2f(t2b[(bm * L4 + k) * 256 + tid]);
  rb[(cz * BM + bm) * 256 + tid] = f2bf_rne(r);
}

// ---------------- build cat matrix, 16B/thread: padded [80][52][768], rows 1..50 ----------------
__global__ void k_build_cat(const u16* __restrict__ t2b, const u16* __restrict__ rb,
                            u16* __restrict__ catm) {
  int idx = blockIdx.x * 256 + threadIdx.x;   // 16B-unit index, < 4000*96
  int u = idx % 96;
  int row = idx / 96;         // bm*50 + li
  int bm = row / L4, li = row - bm * L4;
  uint4 v;
  if (u < 32)      v = *(const uint4*)&t2b[row * 256 + u * 8];
  else if (u < 64) v = *(const uint4*)&rb[bm * 256 + (u - 32) * 8];
  else             v = *(const uint4*)&rb[(BM + bm) * 256 + (u - 64) * 8];
  *(uint4*)&catm[((long long)(bm * 52 + 1 + li)) * 768 + u * 8] = v;
}

// ---------------- final projection + sigmoid: wave-per-row GEMV ----------------
__global__ __launch_bounds__(256) void k_final(
    const u16* __restrict__ d2b, const float* __restrict__ qv,
    const float* __restrict__ b_mlp, float* __restrict__ out) {
  int wv = blockIdx.x * 4 + (threadIdx.x >> 6);
  int ln = threadIdx.x & 63;
  int row0 = wv * 16;
  int b = row0 / 4000;
  float4 q1 = *(const float4*)&qv[2048 + b * 256 + ln * 4];
  float4 q2 = *(const float4*)&qv[2048 + 1024 + b * 256 + ln * 4];
  float bmlp = b_mlp[0];
  for (int r = 0; r < 16; ++r) {
    int row = row0 + r;
    ushort4 v = *(const ushort4*)&d2b[(long long)row * 256 + ln * 4];
    float x0 = bf2f(v.x), x1 = bf2f(v.y), x2 = bf2f(v.z), x3 = bf2f(v.w);
    float p1 = x0 * q1.x + x1 * q1.y + x2 * q1.z + x3 * q1.w;
    float p2 = x0 * q2.x + x1 * q2.y + x2 * q2.z + x3 * q2.w;
    for (int off = 32; off > 0; off >>= 1) {
      p1 += __shfl_down(p1, off, 64);
      p2 += __shfl_down(p2, off, 64);
    }
    if (ln == 0) {
      out[row]         = 1.f / (1.f + expf(-(p1 + bmlp)));
      out[16000 + row] = 1.f / (1.f + expf(-(p2 + bmlp)));
    }
  }
}

// ---------------- host ----------------
extern "C" void kernel_launch(void* const* d_in, const int* in_sizes, int n_in,
                              void* d_out, int out_size, void* d_ws, size_t ws_size,
                              hipStream_t stream) {
  const float* batch    = (const float*)d_in[0];
  const int*   seg_len  = (const int*)d_in[1];
  const float* concept1 = (const float*)d_in[2];
  const float* concept2 = (const float*)d_in[3];
  const float* w_conv1  = (const float*)d_in[4];
  const float* b_conv1  = (const float*)d_in[5];
  const float* w_conv2  = (const float*)d_in[6];
  const float* b_conv2  = (const float*)d_in[7];
  const float* w_ca1    = (const float*)d_in[8];
  const float* w_ca2    = (const float*)d_in[9];
  const float* w_ca3    = (const float*)d_in[10];
  const float* w_dc1    = (const float*)d_in[11];
  const float* b_dc1    = (const float*)d_in[12];
  const float* w_dc2    = (const float*)d_in[13];
  const float* b_dc2    = (const float*)d_in[14];
  const float* w_sim1   = (const float*)d_in[15];
  const float* w_sim2   = (const float*)d_in[16];
  const float* w_mlp    = (const float*)d_in[17];
  const float* b_mlp    = (const float*)d_in[18];
  float* out = (float*)d_out;

  float* ws = (float*)d_ws;
  // workspace (float units) — total 24,477,696 f = 97.9 MB
  const long long off_qv    = 0;          //      4,096
  const long long off_kproj = 4096;       //  1,024,000 fp32
  const long long off_rb    = 1028096;    //     20,480 (u16 40,960)
  const long long off_t1    = 1048576;    //  2,162,688 (t1b [80][104][512]+slack)
  const long long off_t2    = 3211264;    //    524,288 (t2b [4000][256]+slack)
  const long long off_w1b   = 3735552;    //  2,621,440
  const long long off_w2b   = 6356992;    //    327,680
  const long long off_wd1p  = 6684672;    //    786,432
  const long long off_wd2p  = 7471104;    //    262,144
  const long long off_wca2b = 7733248;    //     32,768
  const long long off_BIG   = 7766016;    // 16,711,680 (batchb -> catm/d1b/d2b)

  u16* rb    = (u16*)(ws + off_rb);
  u16* t1b   = (u16*)(ws + off_t1);
  u16* t2b   = (u16*)(ws + off_t2);
  u16* w1b   = (u16*)(ws + off_w1b);
  u16* w2b   = (u16*)(ws + off_w2b);
  u16* wd1p  = (u16*)(ws + off_wd1p);
  u16* wd2p  = (u16*)(ws + off_wd2p);
  u16* wca2b = (u16*)(ws + off_wca2b);
  u16* batchb = (u16*)(ws + off_BIG);               // [80][204][2048] swizzled
  u16* catm   = (u16*)(ws + off_BIG);               // [80][52][768]+slack (after conv1)
  u16* d1b    = (u16*)(ws + off_BIG) + 3342336;     // [80][102][512]+slack
  u16* d2b    = (u16*)(ws + off_BIG) + 7667712;     // [16000][256]

  // --- all prep in one dispatch ---
  k_prep_all<<<dim3(17720), 256, 0, stream>>>(
      batch, w_conv1, w_conv2, w_dc1, w_dc2, w_ca2,
      concept1, concept2, w_ca1, w_sim1, w_sim2, w_mlp,
      batchb, w1b, w2b, wd1p, wd2p, wca2b, ws + off_qv, t1b);

  // --- conv1 + pool + bias -> t1b [80][104][512] SWIZZLED (M=16000,N=512,K=10240)
  k_conv1_gemm<<<dim3(504), 256, 0, stream>>>(
      batchb, w1b, t1b, b_conv1, 16000, 512, 10240, 2048, 32,
      200, 204, 2, 63, 125, 104, 2, 80LL * 204 * 2048);

  // batchb dead -> zero pads of catm / d1b (they overlay it)
  k_zero_pad2<<<dim3(100), 256, 0, stream>>>(catm, d1b);

  // --- conv2 + pool + bias -> t2b [4000][256] plain (M=8000,N=256,K=2560)
  k_conv2_gemm<<<dim3(128), 256, 0, stream>>>(
      t1b, w2b, t2b, b_conv2, 8000, 256, 2560, 512, 8,
      100, 104, 4, 16, 63, 50, 0, 80LL * 104 * 512);

  // --- kproj = t2 @ w_ca2^T -> fp32 [4000][256] (M=4000,N=256,K=256)
  k_kproj_gemm<<<dim3(64), 256, 0, stream>>>(
      t2b, wca2b, ws + off_kproj, nullptr, 4000, 256, 256, 4,
      4000, 4000, 256, 0, 1, 4, 8, 32, 0, 0, 0);

  // --- attention -> rb bf16 [2][80][256]
  k_attention<<<dim3(160), 256, 0, stream>>>(ws + off_kproj, t2b, ws + off_qv,
                                             w_ca3, seg_len, rb);

  // --- cat -> catm padded [80][52][768]  (16B/thread)
  k_build_cat<<<dim3(1500), 256, 0, stream>>>(t2b, rb, catm);

  // --- deconv1: 2 parity convs + bias -> d1b [80][102][512] (M=4000,N=512,K=1536)
  k_dc1_gemm<<<dim3(128, 1, 2), 256, 0, stream>>>(
      catm, wd1p, d1b, b_dc1, 4000, 512, 1536, 24,
      50, 52, 768, 0, 2, 2, 16, 32, 786432LL, 102, 1);

  // --- deconv2: 2 parity convs + bias -> d2b [16000][256] (M=8000,N=256,K=1024)
  k_dc2_gemm<<<dim3(128, 1, 2), 256, 0, stream>>>(
      d1b, wd2p, d2b, b_dc2, 8000, 256, 1024, 16,
      100, 102, 512, 0, 2, 4, 16, 63, 262144LL, 200, 0);

  // --- final dot + sigmoid -> out (sc1 | sc2) fp32
  k_final<<<dim3(250), 256, 0, stream>>>(d2b, ws + off_qv, b_mlp, out);
}

// Round 7
// 700.034 us; speedup vs baseline: 1.2466x; 1.2466x over previous
//
#include <hip/hip_runtime.h>
#include <hip/hip_bf16.h>
#include <math.h>

// Problem constants
#define BB 4
#define MM 20
#define LL 200
#define INC 2048
#define C1 512
#define C2 256
#define CDIM 300
#define DC1 512
#define DC2 256
#define SDIM 1024
#define BM 80           // B*M
#define L2 100          // L/2
#define L4 50           // L/4

typedef unsigned short u16;
typedef __attribute__((ext_vector_type(8))) short bf16x8;
typedef __attribute__((ext_vector_type(4))) float f32x4;

__device__ __forceinline__ u16 f2bf_rne(float f) {
  unsigned u = __float_as_uint(f);
  unsigned r = u + 0x7FFFu + ((u >> 16) & 1u);
  return (u16)(r >> 16);
}
__device__ __forceinline__ float bf2f(u16 v) {
  return __uint_as_float(((unsigned)v) << 16);
}

// async global -> LDS, 16 B per lane. LDS dest = wave-uniform base + lane*16.
__device__ __forceinline__ void gload16(const u16* g, u16* l) {
  __builtin_amdgcn_global_load_lds(
      (const __attribute__((address_space(1))) void*)g,
      (__attribute__((address_space(3))) void*)l, 16, 0, 0);
}

// ======================= conv GEMM with A-dedup (128-row tile) =======================
// R3/R5-verified (201us conv1, VGPR 120, 2 blocks/CU): A staged once per 64-ci
// block into a [160][64] XOR-swizzled row-major tile; frag-order B; tap-inner
// chunks; per wave per chunk 1 A-piece + 4 B-frags, counted vmcnt(5)/(4)/(0);
// double-buffered. KEPT AS DIRECT __global__ TEMPLATE: the R6 wrapper+forceinline
// form perturbed regalloc (VGPR 132) and halved residency -> +88% duration.
template <int SWZO>
__global__ __launch_bounds__(256) void k_gemm_conv(
    const u16* __restrict__ A, const u16* __restrict__ Bw,
    u16* __restrict__ Co, const float* __restrict__ bias,
    int M, int N, int Ktot, int cin, int ncib,
    int lr, int rpad, int px, int yspan, int gy,
    int orpad, int ooff, long long aend) {
  __shared__ __align__(16) u16 At[2][10240];   // [2][160][64]
  __shared__ __align__(16) u16 Bs[2][8192];
  int id = blockIdx.x;
  int k8 = id & 7, j = id >> 3;
  int x = k8 / px, h = k8 - x * px;
  int y = h * yspan + j;
  if (y >= gy) return;
  int row0 = y * 128, col0 = x * 128;
  int tid = threadIdx.x, w = tid >> 6, ln = tid & 63;
  int r15 = ln & 15, q = ln >> 4;

  int n0 = row0 / lr, l0 = row0 - n0 * lr;
  long long prow0 = (long long)n0 * rpad + l0;

  int wrb = (w >> 1) * 64;
  int rlb[4], pp[4];
  #pragma unroll
  for (int mi = 0; mi < 4; ++mi) {
    int rr = wrb + mi * 16 + r15;
    int nc = (row0 + rr) / lr - n0;
    rlb[mi] = rr + 4 * nc;
    pp[mi] = (int)((prow0 + rlb[mi]) & 7);
  }

  long long arow_base = prow0 + w * 40 + (ln >> 3);
  const u16* alim = A + (aend - 8);
  auto stA = [&](int cib_, int pc) {
    const u16* src = A + (arow_base + pc * 8) * cin + cib_ * 64 + (ln & 7) * 8;
    if (src > alim) src = alim;
    gload16(src, At[cib_ & 1] + (w * 40 + pc * 8) * 64);
  };

  const u16* gb[4];
  #pragma unroll
  for (int i = 0; i < 4; ++i) {
    int f = 4 * w + i, blk = f >> 1, ks = f & 1;
    int klocal = ks * 32 + q * 8;
    int br = col0 + blk * 16 + r15;
    gb[i] = Bw + ((long long)br * Ktot + klocal);
  }
  int wbase = 4 * w * 512;

  f32x4 acc[4][4];
  #pragma unroll
  for (int i = 0; i < 4; ++i)
    #pragma unroll
    for (int j2 = 0; j2 < 4; ++j2) acc[i][j2] = (f32x4){0.f, 0.f, 0.f, 0.f};
  int wc2 = (w & 1) * 4;

  #pragma unroll
  for (int pc = 0; pc < 5; ++pc) stA(0, pc);
  #pragma unroll
  for (int i = 0; i < 4; ++i) gload16(gb[i], Bs[0] + wbase + i * 512);
  #pragma unroll
  for (int i = 0; i < 4; ++i) gb[i] += cin;
  int ts = 1;
  asm volatile("s_waitcnt vmcnt(0)" ::: "memory");
  __builtin_amdgcn_s_barrier();

  long long bwrap = 64 - 4 * (long long)cin;
  for (int cib = 0; cib < ncib; ++cib) {
    bool lastcib = (cib == ncib - 1);
    #pragma unroll
    for (int t = 0; t < 5; ++t) {
      bool lastc = lastcib && (t == 4);
      if (!lastcib) stA(cib + 1, t);
      if (!lastc) {
        int bufn = (cib + t + 1) & 1;
        #pragma unroll
        for (int i = 0; i < 4; ++i) gload16(gb[i], Bs[bufn] + wbase + i * 512);
        long long d = (ts == 4) ? bwrap : (long long)cin;
        ts = (ts == 4) ? 0 : ts + 1;
        #pragma unroll
        for (int i = 0; i < 4; ++i) gb[i] += d;
      }
      if (lastc)        asm volatile("s_waitcnt vmcnt(0)" ::: "memory");
      else if (lastcib) asm volatile("s_waitcnt vmcnt(4)" ::: "memory");
      else              asm volatile("s_waitcnt vmcnt(5)" ::: "memory");
      __builtin_amdgcn_s_barrier();
      __builtin_amdgcn_sched_barrier(0);
      const u16* Ab = At[cib & 1];
      const u16* Bb = Bs[(cib + t) & 1];
      int rof[4], pr8[4];
      #pragma unroll
      for (int mi = 0; mi < 4; ++mi) {
        rof[mi] = (rlb[mi] + t) * 64;
        pr8[mi] = (pp[mi] + t) & 7;
      }
      #pragma unroll
      for (int ks = 0; ks < 2; ++ks) {
        bf16x8 af[4], bf[4];
        #pragma unroll
        for (int mi = 0; mi < 4; ++mi)
          af[mi] = *(const bf16x8*)&Ab[rof[mi] + (((ks * 4 + q) ^ pr8[mi]) * 8)];
        #pragma unroll
        for (int ni = 0; ni < 4; ++ni)
          bf[ni] = *(const bf16x8*)&Bb[(((wc2 + ni) * 2 + ks) * 512) + ln * 8];
        #pragma unroll
        for (int mi = 0; mi < 4; ++mi)
          #pragma unroll
          for (int ni = 0; ni < 4; ++ni)
            acc[mi][ni] = __builtin_amdgcn_mfma_f32_16x16x32_bf16(
                af[mi], bf[ni], acc[mi][ni], 0, 0, 0);
      }
      __builtin_amdgcn_sched_barrier(0);
      __builtin_amdgcn_s_barrier();
    }
  }

  int q4 = q * 4;
  int wrow = (w >> 1) * 64, wcol = (w & 1) * 64;
  int lrh = lr >> 1;
  #pragma unroll
  for (int mi = 0; mi < 4; ++mi) {
    int gbase = row0 + wrow + mi * 16 + q4;
    #pragma unroll
    for (int p = 0; p < 2; ++p) {
      int grow = gbase + 2 * p;
      if (grow < M) {
        int prow = grow >> 1;
        int n = prow / lrh, ll = prow - n * lrh;
        long long orow = (long long)n * orpad + ooff + ll;
        int key = SWZO ? ((int)(orow & 7) << 3) : 0;
        #pragma unroll
        for (int ni = 0; ni < 4; ++ni) {
          int col = col0 + wcol + ni * 16 + r15;
          float v = fmaxf(acc[mi][ni][2 * p], acc[mi][ni][2 * p + 1]) + bias[col];
          Co[orow * N + (col ^ key)] = f2bf_rne(v);
        }
      }
    }
  }
}

// ---------------- generic bf16-MFMA NT GEMM (kproj, deconvs) ----------------
// R5-verified direct template form.
#define EP_PLAIN 0
#define EP_POOL  1
#define EP_ILV   2

template <int EP>
__global__ __launch_bounds__(256) void k_gemm(
    const u16* __restrict__ A, const u16* __restrict__ Bw,
    void* __restrict__ Co, const float* __restrict__ bias,
    int M, int N, int Ktot, int nchunk,
    int lr, int rpad, int cin, int off0c, int taps,
    int px, int yspan, int gy, long long sB, int orpad, int ooff) {
  __shared__ __align__(16) u16 As[2][8192];
  __shared__ __align__(16) u16 Bs[2][8192];
  int id = blockIdx.x;
  int k8 = id & 7, j = id >> 3;
  int x = k8 / px, h = k8 - x * px;
  int y = h * yspan + j;
  if (y >= gy) return;
  int z = blockIdx.z;
  int off0 = (EP == EP_ILV) ? z : off0c;
  int row0 = y * 128, col0 = x * 128;
  int tid = threadIdx.x, w = tid >> 6, ln = tid & 63;
  const u16* Bz = Bw + (long long)z * sB;

  const u16* ga[4];
  const u16* gb[4];
  #pragma unroll
  for (int i = 0; i < 4; ++i) {
    int f = 4 * w + i, blk = f >> 1, ks = f & 1;
    int klocal = ks * 32 + (ln >> 4) * 8;
    int ar = row0 + blk * 16 + (ln & 15);
    int n_ = ar / lr, l_ = ar - n_ * lr;
    ga[i] = A + ((long long)(n_ * rpad + l_ + off0) * cin + klocal);
    int br = col0 + blk * 16 + (ln & 15);
    gb[i] = Bz + ((long long)br * Ktot + klocal);
  }
  int wbase = 4 * w * 512;

  f32x4 acc[4][4];
  #pragma unroll
  for (int i = 0; i < 4; ++i)
    #pragma unroll
    for (int j2 = 0; j2 < 4; ++j2) acc[i][j2] = (f32x4){0.f, 0.f, 0.f, 0.f};

  int wr2 = (w >> 1) * 4;
  int wc2 = (w & 1) * 4;

  long long dstep = cin;
  long long dwrap = 64 - (long long)(taps - 1) * cin;
  int tc = 0;

  #pragma unroll
  for (int i = 0; i < 4; ++i) {
    gload16(ga[i], As[0] + wbase + i * 512);
    gload16(gb[i], Bs[0] + wbase + i * 512);
  }
  {
    long long d = (tc == taps - 1) ? dwrap : dstep;
    tc = (tc == taps - 1) ? 0 : tc + 1;
    #pragma unroll
    for (int i = 0; i < 4; ++i) { ga[i] += d; gb[i] += d; }
  }

  for (int c = 0; c < nchunk; ++c) {
    int cur = c & 1;
    if (c + 1 < nchunk) {
      u16* dA = As[cur ^ 1] + wbase;
      u16* dB = Bs[cur ^ 1] + wbase;
      #pragma unroll
      for (int i = 0; i < 4; ++i) {
        gload16(ga[i], dA + i * 512);
        gload16(gb[i], dB + i * 512);
      }
      long long d = (tc == taps - 1) ? dwrap : dstep;
      tc = (tc == taps - 1) ? 0 : tc + 1;
      #pragma unroll
      for (int i = 0; i < 4; ++i) { ga[i] += d; gb[i] += d; }
      asm volatile("s_waitcnt vmcnt(8)" ::: "memory");
    } else {
      asm volatile("s_waitcnt vmcnt(0)" ::: "memory");
    }
    __builtin_amdgcn_s_barrier();
    __builtin_amdgcn_sched_barrier(0);
    #pragma unroll
    for (int ks = 0; ks < 2; ++ks) {
      bf16x8 af[4], bf[4];
      #pragma unroll
      for (int mi = 0; mi < 4; ++mi)
        af[mi] = *(const bf16x8*)&As[cur][(((wr2 + mi) * 2 + ks) * 512) + ln * 8];
      #pragma unroll
      for (int ni = 0; ni < 4; ++ni)
        bf[ni] = *(const bf16x8*)&Bs[cur][(((wc2 + ni) * 2 + ks) * 512) + ln * 8];
      #pragma unroll
      for (int mi = 0; mi < 4; ++mi)
        #pragma unroll
        for (int ni = 0; ni < 4; ++ni)
          acc[mi][ni] = __builtin_amdgcn_mfma_f32_16x16x32_bf16(
              af[mi], bf[ni], acc[mi][ni], 0, 0, 0);
    }
    __builtin_amdgcn_sched_barrier(0);
    __builtin_amdgcn_s_barrier();
  }

  int c15 = ln & 15, q4 = (ln >> 4) * 4;
  int wrow = (w >> 1) * 64, wcol = (w & 1) * 64;
  if (EP == EP_PLAIN) {
    float* Cz = (float*)Co;
    #pragma unroll
    for (int mi = 0; mi < 4; ++mi) {
      int gbase = row0 + wrow + mi * 16 + q4;
      #pragma unroll
      for (int r = 0; r < 4; ++r) {
        int grow = gbase + r;
        if (grow < M) {
          #pragma unroll
          for (int ni = 0; ni < 4; ++ni) {
            int col = col0 + wcol + ni * 16 + c15;
            Cz[(long long)grow * N + col] = acc[mi][ni][r];
          }
        }
      }
    }
  } else if (EP == EP_POOL) {
    u16* Cz = (u16*)Co;
    int lrh = lr >> 1;
    #pragma unroll
    for (int mi = 0; mi < 4; ++mi) {
      int gbase = row0 + wrow + mi * 16 + q4;
      #pragma unroll
      for (int p = 0; p < 2; ++p) {
        int grow = gbase + 2 * p;
        if (grow < M) {
          int prow = grow >> 1;
          int n = prow / lrh, ll = prow - n * lrh;
          long long orow = (long long)n * orpad + ooff + ll;
          #pragma unroll
          for (int ni = 0; ni < 4; ++ni) {
            int col = col0 + wcol + ni * 16 + c15;
            float v = fmaxf(acc[mi][ni][2 * p], acc[mi][ni][2 * p + 1]) + bias[col];
            Cz[orow * N + col] = f2bf_rne(v);
          }
        }
      }
    }
  } else {  // EP_ILV
    u16* Cz = (u16*)Co;
    #pragma unroll
    for (int mi = 0; mi < 4; ++mi) {
      int gbase = row0 + wrow + mi * 16 + q4;
      #pragma unroll
      for (int r = 0; r < 4; ++r) {
        int grow = gbase + r;
        if (grow < M) {
          int n = grow / lr, l = grow - n * lr;
          long long orow = (long long)n * orpad + ooff + 2 * l + z;
          #pragma unroll
          for (int ni = 0; ni < 4; ++ni) {
            int col = col0 + wcol + ni * 16 + c15;
            Cz[orow * N + col] = f2bf_rne(acc[mi][ni][r] + bias[col]);
          }
        }
      }
    }
  }
}

// ================= MEGA-PREP: all independent prep work in ONE dispatch =================
// Region map (blockIdx.x):
//   [0, 16320)          cast+pad+swizzle batch -> batchb [80][204][2048]
//   [16320, 16832)      conv1 weight [co][ci][5] -> [co][5][ci]   (512 co-blocks)
//   [16832, 17088)      conv2 weight transpose                     (256)
//   [17088, 17472)      deconv1 weight -> per-parity               (384)
//   [17472, 17600)      deconv2 weight -> per-parity               (128)
//   [17600, 17632)      w_ca2 fp32->bf16                           (32)
//   [17632, 17640)      small q/v precompute                       (8)
//   [17640, 17720)      t1b pad-row zeroing                        (80)
__global__ __launch_bounds__(256) void k_prep_all(
    const float* __restrict__ batch, const float* __restrict__ w_conv1,
    const float* __restrict__ w_conv2, const float* __restrict__ w_dc1,
    const float* __restrict__ w_dc2, const float* __restrict__ w_ca2,
    const float* __restrict__ concept1, const float* __restrict__ concept2,
    const float* __restrict__ w_ca1, const float* __restrict__ w_sim1,
    const float* __restrict__ w_sim2, const float* __restrict__ w_mlp,
    u16* __restrict__ batchb, u16* __restrict__ w1b, u16* __restrict__ w2b,
    u16* __restrict__ wd1p, u16* __restrict__ wd2p, u16* __restrict__ wca2b,
    float* __restrict__ qv, u16* __restrict__ t1b) {
  __shared__ __align__(16) u16 sh[10240];   // 20 KB, reused per-branch
  int bid = blockIdx.x;
  int tid = threadIdx.x;

  if (bid < 16320) {
    int idx = bid * 256 + tid;
    int c8 = idx % 256;
    int pi = (idx / 256) % 204;
    int n  = idx / (256 * 204);
    uint4 o = make_uint4(0u, 0u, 0u, 0u);
    if (pi >= 2 && pi < 202) {
      const float* p = batch + ((long long)(n * 200 + pi - 2) * 2048 + c8 * 8);
      float4 a = *(const float4*)p;
      float4 b = *(const float4*)(p + 4);
      o.x = (unsigned)f2bf_rne(a.x) | ((unsigned)f2bf_rne(a.y) << 16);
      o.y = (unsigned)f2bf_rne(a.z) | ((unsigned)f2bf_rne(a.w) << 16);
      o.z = (unsigned)f2bf_rne(b.x) | ((unsigned)f2bf_rne(b.y) << 16);
      o.w = (unsigned)f2bf_rne(b.z) | ((unsigned)f2bf_rne(b.w) << 16);
    }
    int key = (n * 204 + pi) & 7;
    long long pos = ((long long)(n * 204 + pi)) * 256 + (c8 ^ key);
    *(uint4*)(batchb + pos * 8) = o;
  } else if (bid < 17088) {
    const float* in; u16* out; int Cin, co;
    if (bid < 16832) { in = w_conv1; out = w1b; Cin = INC; co = bid - 16320; }
    else             { in = w_conv2; out = w2b; Cin = C1;  co = bid - 16832; }
    int n = Cin * 5;
    const float* src = in + (long long)co * n;
    for (int i = tid; i < n; i += 256) sh[i] = f2bf_rne(src[i]);
    __syncthreads();
    u16* dst = out + (long long)co * n;
    int n8 = n >> 3;
    for (int j8 = tid; j8 < n8; j8 += 256) {
      int j = j8 * 8;
      int t = j / Cin, ci = j - t * Cin;
      u16 tmp[8];
      #pragma unroll
      for (int e = 0; e < 8; ++e) tmp[e] = sh[(ci + e) * 5 + t];
      uint4 o;
      o.x = tmp[0] | ((unsigned)tmp[1] << 16);
      o.y = tmp[2] | ((unsigned)tmp[3] << 16);
      o.z = tmp[4] | ((unsigned)tmp[5] << 16);
      o.w = tmp[6] | ((unsigned)tmp[7] << 16);
      *(uint4*)&dst[j] = o;
    }
  } else if (bid < 17600) {
    u16 (*l)[65] = (u16(*)[65])sh;
    const float* in; u16* out; int Cin, Cout, b2;
    if (bid < 17472) { in = w_dc1; out = wd1p; Cin = 3 * C2; Cout = DC1; b2 = bid - 17088; }
    else             { in = w_dc2; out = wd2p; Cin = DC1;    Cout = DC2; b2 = bid - 17472; }
    int C = Cout * 4;
    int nci = Cin >> 6;
    int ci0 = (b2 % nci) << 6;
    int c0  = (b2 / nci) << 6;
    int cc = tid & 63, rr = tid >> 6;
    #pragma unroll 4
    for (int p = 0; p < 16; ++p) {
      int r = rr + p * 4;
      l[r][cc] = f2bf_rne(in[(long long)(ci0 + r) * C + c0 + cc]);
    }
    __syncthreads();
    #pragma unroll 4
    for (int p = 0; p < 16; ++p) {
      int cl = rr + p * 4;
      int c = c0 + cl;
      int co = c >> 2, t = c & 3;
      int z = (3 - t) & 1, tt = (3 - t) >> 1;
      out[(((long long)z * Cout + co) * 2 + tt) * Cin + ci0 + cc] = l[cc][cl];
    }
  } else if (bid < 17632) {
    int idx = (bid - 17600) * 256 + tid;
    const float4* p = (const float4*)w_ca2 + (long long)idx * 2;
    float4 a = p[0], b = p[1];
    uint4 o;
    o.x = (unsigned)f2bf_rne(a.x) | ((unsigned)f2bf_rne(a.y) << 16);
    o.y = (unsigned)f2bf_rne(a.z) | ((unsigned)f2bf_rne(a.w) << 16);
    o.z = (unsigned)f2bf_rne(b.x) | ((unsigned)f2bf_rne(b.y) << 16);
    o.w = (unsigned)f2bf_rne(b.z) | ((unsigned)f2bf_rne(b.w) << 16);
    *(uint4*)(wca2b + (long long)idx * 8) = o;
  } else if (bid < 17640) {
    float* cvec = (float*)sh;            // [300]
    float* chat = (float*)sh + 320;      // [1024]
    int b2 = bid - 17632;
    int cz = b2 >> 2;
    int b  = b2 & 3;
    const float* con = cz ? concept2 : concept1;
    for (int j = tid; j < CDIM; j += 256) cvec[j] = con[b * CDIM + j];
    __syncthreads();
    float accq = 0.f;
    for (int j = 0; j < CDIM; ++j) accq += cvec[j] * w_ca1[tid * CDIM + j];
    qv[(cz * 4 + b) * 256 + tid] = accq;
    for (int i = 0; i < 4; ++i) {
      int s = tid + i * 256;
      float a2 = 0.f;
      for (int j = 0; j < CDIM; ++j) a2 += cvec[j] * w_sim2[s * CDIM + j];
      chat[s] = a2 * w_mlp[s];
    }
    __syncthreads();
    float v = 0.f;
    for (int s = 0; s < SDIM; ++s) v += w_sim1[s * 256 + tid] * chat[s];
    qv[2048 + (cz * 4 + b) * 256 + tid] = v;
  } else {
    int idx = (bid - 17640) * 256 + tid;   // < 20480
    int c = idx % 64;
    int pr = (idx / 64) % 4;
    int n = idx / 256;
    int row = (pr < 2) ? pr : 100 + pr;
    *(uint4*)(t1b + ((long long)(n * 104 + row) * 64 + c) * 8) = make_uint4(0, 0, 0, 0);
  }
}

// ---------------- post-conv1 zero-pads (catm rows {0,51}, d1b rows {0,101}) ----------------
__global__ void k_zero_pad2(u16* __restrict__ catm, u16* __restrict__ d1b) {
  int idx = blockIdx.x * 256 + threadIdx.x;
  if (idx < 15360) {
    int c = idx % 96;
    int pr = (idx / 96) & 1;
    int n = idx / 192;
    int row = pr ? 51 : 0;
    *(uint4*)(catm + ((long long)(n * 52 + row) * 96 + c) * 8) = make_uint4(0, 0, 0, 0);
  } else {
    int j = idx - 15360;      // < 10240
    int c = j % 64;
    int pr = (j / 64) & 1;
    int n = j / 128;
    int row = pr ? 101 : 0;
    *(uint4*)(d1b + ((long long)(n * 102 + row) * 64 + c) * 8) = make_uint4(0, 0, 0, 0);
  }
}

// ---------------- attention: wave-parallel scores + softmax + weighted sum ----------------
__global__ __launch_bounds__(256) void k_attention(
    const float* __restrict__ kproj, const u16* __restrict__ t2b,
    const float* __restrict__ qv, const float* __restrict__ w_ca3,
    const int* __restrict__ seg_len, u16* __restrict__ rb) {
  int bm = blockIdx.x % BM;
  int cz = blockIdx.x / BM;
  int b = bm / MM;
  int tid = threadIdx.x, w = tid >> 6, ln = tid & 63;
  __shared__ float sq[256], sw[256], sa[L4 + 14];
  sq[tid] = qv[(cz * 4 + b) * 256 + tid];
  sw[tid] = w_ca3[tid];
  __syncthreads();
  int kmax = (seg_len[bm] + 3) >> 2;
  for (int k = w; k < L4; k += 4) {
    float val = 0.f;
    #pragma unroll
    for (int i = 0; i < 4; ++i) {
      int c = ln + 64 * i;
      val += tanhf(sq[c] + kproj[(bm * L4 + k) * 256 + c]) * sw[c];
    }
    for (int off = 32; off > 0; off >>= 1) val += __shfl_down(val, off, 64);
    if (ln == 0) sa[k] = (k < kmax) ? val : -1e15f;
  }
  __syncthreads();
  if (w == 0) {
    float sv = (ln < L4) ? sa[ln] : -3e38f;
    float mx = sv;
    for (int off = 32; off > 0; off >>= 1) mx = fmaxf(mx, __shfl_down(mx, off, 64));
    mx = __shfl(mx, 0, 64);
    float e = (ln < L4) ? expf(sv - mx) : 0.f;
    float s = e;
    for (int off = 32; off > 0; off >>= 1) s += __shfl_down(s, off, 64);
    s = __shfl(s, 0, 64);
    if (ln < L4) sa[ln] = e / s;
  }
  __syncthreads();
  float r = 0.f;
  for (int k = 0; k < L4; ++k) r += sa[k] * bf2f(t2b[(bm * L4 + k) * 256 + tid]);
  rb[(cz * BM + bm) * 256 + tid] = f2bf_rne(r);
}

// ---------------- build cat matrix, 16B/thread: padded [80][52][768], rows 1..50 ----------------
__global__ void k_build_cat(const u16* __restrict__ t2b, const u16* __restrict__ rb,
                            u16* __restrict__ catm) {
  int idx = blockIdx.x * 256 + threadIdx.x;   // 16B-unit index, < 4000*96
  int u = idx % 96;
  int row = idx / 96;         // bm*50 + li
  int bm = row / L4, li = row - bm * L4;
  uint4 v;
  if (u < 32)      v = *(const uint4*)&t2b[row * 256 + u * 8];
  else if (u < 64) v = *(const uint4*)&rb[bm * 256 + (u - 32) * 8];
  else             v = *(const uint4*)&rb[(BM + bm) * 256 + (u - 64) * 8];
  *(uint4*)&catm[((long long)(bm * 52 + 1 + li)) * 768 + u * 8] = v;
}

// ---------------- final projection + sigmoid: wave-per-row GEMV ----------------
__global__ __launch_bounds__(256) void k_final(
    const u16* __restrict__ d2b, const float* __restrict__ qv,
    const float* __restrict__ b_mlp, float* __restrict__ out) {
  int wv = blockIdx.x * 4 + (threadIdx.x >> 6);
  int ln = threadIdx.x & 63;
  int row0 = wv * 16;
  int b = row0 / 4000;
  float4 q1 = *(const float4*)&qv[2048 + b * 256 + ln * 4];
  float4 q2 = *(const float4*)&qv[2048 + 1024 + b * 256 + ln * 4];
  float bmlp = b_mlp[0];
  for (int r = 0; r < 16; ++r) {
    int row = row0 + r;
    ushort4 v = *(const ushort4*)&d2b[(long long)row * 256 + ln * 4];
    float x0 = bf2f(v.x), x1 = bf2f(v.y), x2 = bf2f(v.z), x3 = bf2f(v.w);
    float p1 = x0 * q1.x + x1 * q1.y + x2 * q1.z + x3 * q1.w;
    float p2 = x0 * q2.x + x1 * q2.y + x2 * q2.z + x3 * q2.w;
    for (int off = 32; off > 0; off >>= 1) {
      p1 += __shfl_down(p1, off, 64);
      p2 += __shfl_down(p2, off, 64);
    }
    if (ln == 0) {
      out[row]         = 1.f / (1.f + expf(-(p1 + bmlp)));
      out[16000 + row] = 1.f / (1.f + expf(-(p2 + bmlp)));
    }
  }
}

// ---------------- host ----------------
extern "C" void kernel_launch(void* const* d_in, const int* in_sizes, int n_in,
                              void* d_out, int out_size, void* d_ws, size_t ws_size,
                              hipStream_t stream) {
  const float* batch    = (const float*)d_in[0];
  const int*   seg_len  = (const int*)d_in[1];
  const float* concept1 = (const float*)d_in[2];
  const float* concept2 = (const float*)d_in[3];
  const float* w_conv1  = (const float*)d_in[4];
  const float* b_conv1  = (const float*)d_in[5];
  const float* w_conv2  = (const float*)d_in[6];
  const float* b_conv2  = (const float*)d_in[7];
  const float* w_ca1    = (const float*)d_in[8];
  const float* w_ca2    = (const float*)d_in[9];
  const float* w_ca3    = (const float*)d_in[10];
  const float* w_dc1    = (const float*)d_in[11];
  const float* b_dc1    = (const float*)d_in[12];
  const float* w_dc2    = (const float*)d_in[13];
  const float* b_dc2    = (const float*)d_in[14];
  const float* w_sim1   = (const float*)d_in[15];
  const float* w_sim2   = (const float*)d_in[16];
  const float* w_mlp    = (const float*)d_in[17];
  const float* b_mlp    = (const float*)d_in[18];
  float* out = (float*)d_out;

  float* ws = (float*)d_ws;
  // workspace (float units) — total 24,477,696 f = 97.9 MB
  const long long off_qv    = 0;          //      4,096
  const long long off_kproj = 4096;       //  1,024,000 fp32
  const long long off_rb    = 1028096;    //     20,480 (u16 40,960)
  const long long off_t1    = 1048576;    //  2,162,688 (t1b [80][104][512]+slack)
  const long long off_t2    = 3211264;    //    524,288 (t2b [4000][256]+slack)
  const long long off_w1b   = 3735552;    //  2,621,440
  const long long off_w2b   = 6356992;    //    327,680
  const long long off_wd1p  = 6684672;    //    786,432
  const long long off_wd2p  = 7471104;    //    262,144
  const long long off_wca2b = 7733248;    //     32,768
  const long long off_BIG   = 7766016;    // 16,711,680 (batchb -> catm/d1b/d2b)

  u16* rb    = (u16*)(ws + off_rb);
  u16* t1b   = (u16*)(ws + off_t1);
  u16* t2b   = (u16*)(ws + off_t2);
  u16* w1b   = (u16*)(ws + off_w1b);
  u16* w2b   = (u16*)(ws + off_w2b);
  u16* wd1p  = (u16*)(ws + off_wd1p);
  u16* wd2p  = (u16*)(ws + off_wd2p);
  u16* wca2b = (u16*)(ws + off_wca2b);
  u16* batchb = (u16*)(ws + off_BIG);               // [80][204][2048] swizzled
  u16* catm   = (u16*)(ws + off_BIG);               // [80][52][768]+slack (after conv1)
  u16* d1b    = (u16*)(ws + off_BIG) + 3342336;     // [80][102][512]+slack
  u16* d2b    = (u16*)(ws + off_BIG) + 7667712;     // [16000][256]

  // --- all prep in one dispatch ---
  k_prep_all<<<dim3(17720), 256, 0, stream>>>(
      batch, w_conv1, w_conv2, w_dc1, w_dc2, w_ca2,
      concept1, concept2, w_ca1, w_sim1, w_sim2, w_mlp,
      batchb, w1b, w2b, wd1p, wd2p, wca2b, ws + off_qv, t1b);

  // --- conv1 + pool + bias -> t1b [80][104][512] SWIZZLED (M=16000,N=512,K=10240)
  k_gemm_conv<1><<<dim3(504), 256, 0, stream>>>(
      batchb, w1b, t1b, b_conv1, 16000, 512, 10240, 2048, 32,
      200, 204, 2, 63, 125, 104, 2, 80LL * 204 * 2048);

  // batchb dead -> zero pads of catm / d1b (they overlay it)
  k_zero_pad2<<<dim3(100), 256, 0, stream>>>(catm, d1b);

  // --- conv2 + pool + bias -> t2b [4000][256] plain (M=8000,N=256,K=2560)
  k_gemm_conv<0><<<dim3(128), 256, 0, stream>>>(
      t1b, w2b, t2b, b_conv2, 8000, 256, 2560, 512, 8,
      100, 104, 4, 16, 63, 50, 0, 80LL * 104 * 512);

  // --- kproj = t2 @ w_ca2^T -> fp32 [4000][256] (M=4000,N=256,K=256)
  k_gemm<EP_PLAIN><<<dim3(64), 256, 0, stream>>>(
      t2b, wca2b, ws + off_kproj, nullptr, 4000, 256, 256, 4,
      4000, 4000, 256, 0, 1, 4, 8, 32, 0, 0, 0);

  // --- attention -> rb bf16 [2][80][256]
  k_attention<<<dim3(160), 256, 0, stream>>>(ws + off_kproj, t2b, ws + off_qv,
                                             w_ca3, seg_len, rb);

  // --- cat -> catm padded [80][52][768]  (16B/thread)
  k_build_cat<<<dim3(1500), 256, 0, stream>>>(t2b, rb, catm);

  // --- deconv1: 2 parity convs + bias -> d1b [80][102][512] (M=4000,N=512,K=1536)
  k_gemm<EP_ILV><<<dim3(128, 1, 2), 256, 0, stream>>>(
      catm, wd1p, d1b, b_dc1, 4000, 512, 1536, 24,
      50, 52, 768, 0, 2, 2, 16, 32, 786432LL, 102, 1);

  // --- deconv2: 2 parity convs + bias -> d2b [16000][256] (M=8000,N=256,K=1024)
  k_gemm<EP_ILV><<<dim3(128, 1, 2), 256, 0, stream>>>(
      d1b, wd2p, d2b, b_dc2, 8000, 256, 1024, 16,
      100, 102, 512, 0, 2, 4, 16, 63, 262144LL, 200, 0);

  // --- final dot + sigmoid -> out (sc1 | sc2) fp32
  k_final<<<dim3(250), 256, 0, stream>>>(d2b, ws + off_qv, b_mlp, out);
}